// Round 1
// 706.907 us; speedup vs baseline: 1.0836x; 1.0836x over previous
//
#include <hip/hip_runtime.h>
#include <hip/hip_bf16.h>

// AttentionLayer, B=8, QN=KN=2048, DIN=DPROJ=1024. ALL float tensors are f32
// (threshold 2.33e-3 = 2% of ref absmax). Internals in bf16 MFMA.
//
// Pipeline (9 launches):
//   cvt Wq,Wk -> bf16 (scratch in dead ctx region of d_out)
//   cvt value -> bf16 (same scratch region)
//   Pq  = query·Wqb^T + bq      gemm_af32 (A f32 staged+cvt, B bf16 gld_lds) -> ws
//   Pk  = key·Wkb^T + bk        gemm_af32 -> ws
//   PvT = (Wv f32)·vb^T + bv[m] gemm_af32 -> ws   [PvT[d][i], ldc=16384]
//   S   = Pq·Pk^T/32            gemm_score -> bf16 packed into low half of each
//                               f32 attn row (row pitch stays 8192 B)
//   softmax: read packed bf16 scores, write f32 attn in place + bf16 attnb -> ws
//   ctx = attnb·PvT^T           gemm_bf16 -> f32 ctx (overwrites the Wb/vb scratch)

typedef __bf16 bf16;
typedef __bf16 bf16x4 __attribute__((ext_vector_type(4)));
typedef __bf16 bf16x8 __attribute__((ext_vector_type(8)));
typedef float f32x4 __attribute__((ext_vector_type(4)));

#define TILE 128
#define BK 32

__device__ __forceinline__ void gld_lds16(const bf16* g, bf16* l) {
  __builtin_amdgcn_global_load_lds(
      (const __attribute__((address_space(1))) void*)g,
      (__attribute__((address_space(3))) void*)l, 16, 0, 0);
}

// ---------------- f32 -> bf16 conversion (memory-bound) ----------------
__global__ __launch_bounds__(256)
void cvt_f32_bf16(const float* __restrict__ src, bf16* __restrict__ dst, int n)
{
  long i = ((long)blockIdx.x * 256 + threadIdx.x) * 8;
  if (i >= n) return;
  f32x4 a = *(const f32x4*)&src[i];
  f32x4 b = *(const f32x4*)&src[i + 4];
  bf16x8 o;
  o[0] = (bf16)a[0]; o[1] = (bf16)a[1]; o[2] = (bf16)a[2]; o[3] = (bf16)a[3];
  o[4] = (bf16)b[0]; o[5] = (bf16)b[1]; o[6] = (bf16)b[2]; o[7] = (bf16)b[3];
  *(bf16x8*)&dst[i] = o;
}

// ---------------- GEMM: A f32 (explicit cvt staging), B bf16 (gld_lds) -----
// C[m][n] = sum_k A[m][k]*Bt[n][k] + bias   (bias_mode 1 = bias[n], 2 = bias[m])
// C output bf16.
__global__ __launch_bounds__(256, 2)
void gemm_af32(const float* __restrict__ A, int lda,
               const bf16* __restrict__ Bt, int ldb,
               bf16* __restrict__ C, int ldc,
               const float* __restrict__ bias, int bias_mode, int K)
{
  __shared__ bf16 As[TILE * BK];
  __shared__ bf16 Bs[TILE * BK];
  const int tid = threadIdx.x;
  const int wave = tid >> 6, lane = tid & 63;
  const int wm = (wave >> 1) * 64, wn = (wave & 1) * 64;
  const long m0 = (long)blockIdx.x * TILE;
  const long n0 = (long)blockIdx.y * TILE;

  f32x4 acc[4][4] = {};
  const int fr = lane & 15, fq = lane >> 4;

  // B staging via global_load_lds (16B/lane, 2 issues per k-step)
  const int srow = tid >> 2, scol = (tid & 3) * 8;
  const bf16* Bg0 = Bt + (n0 + srow) * (long)ldb + scol;
  const bf16* Bg1 = Bt + (n0 + 64 + srow) * (long)ldb + scol;
  bf16* Bl0 = &Bs[tid * 8];
  bf16* Bl1 = &Bs[(256 + tid) * 8];

  for (int k0 = 0; k0 < K; k0 += BK) {
    __syncthreads();
    gld_lds16(Bg0 + k0, Bl0);
    gld_lds16(Bg1 + k0, Bl1);
#pragma unroll
    for (int j = 0; j < 4; ++j) {
      int c = j * 256 + tid;             // 1024 chunks of 4 f32
      int row = c >> 3, col = (c & 7) * 4;
      f32x4 av = *(const f32x4*)&A[(m0 + row) * (long)lda + k0 + col];
      bf16x4 ab;
      ab[0] = (bf16)av[0]; ab[1] = (bf16)av[1];
      ab[2] = (bf16)av[2]; ab[3] = (bf16)av[3];
      *(bf16x4*)&As[row * BK + col] = ab;
    }
    __syncthreads();

    bf16x8 af[4], bg[4];
#pragma unroll
    for (int i = 0; i < 4; ++i)
      af[i] = *(const bf16x8*)&As[(wm + i * 16 + fr) * BK + fq * 8];
#pragma unroll
    for (int i = 0; i < 4; ++i)
      bg[i] = *(const bf16x8*)&Bs[(wn + i * 16 + fr) * BK + fq * 8];
#pragma unroll
    for (int mi = 0; mi < 4; ++mi)
#pragma unroll
      for (int ni = 0; ni < 4; ++ni)
        acc[mi][ni] = __builtin_amdgcn_mfma_f32_16x16x32_bf16(
            af[mi], bg[ni], acc[mi][ni], 0, 0, 0);
  }

  const int cc = lane & 15, cq = lane >> 4;  // C/D: col=lane&15, row=quad*4+reg
#pragma unroll
  for (int mi = 0; mi < 4; ++mi)
#pragma unroll
    for (int ni = 0; ni < 4; ++ni)
#pragma unroll
      for (int r = 0; r < 4; ++r) {
        int row = wm + mi * 16 + cq * 4 + r;
        int col = wn + ni * 16 + cc;
        float v = acc[mi][ni][r];
        if (bias_mode == 1) v += bias[n0 + col];
        else if (bias_mode == 2) v += bias[m0 + row];
        C[(m0 + row) * (long)ldc + (n0 + col)] = (bf16)v;
      }
}

// ---------------- GEMM: bf16 in (gld_lds), f32 out (ctx) ----------------
__global__ __launch_bounds__(256, 2)
void gemm_bf16(const bf16* __restrict__ A, int lda, long sA,
               const bf16* __restrict__ Bt, int ldb, long sB,
               float* __restrict__ C, int ldc, long sC,
               int K, float scale)
{
  __shared__ bf16 As[TILE * BK];
  __shared__ bf16 Bs[TILE * BK];
  const int tid = threadIdx.x;
  const int wave = tid >> 6, lane = tid & 63;
  const int wm = (wave >> 1) * 64, wn = (wave & 1) * 64;
  const long m0 = (long)blockIdx.x * TILE;
  const long n0 = (long)blockIdx.y * TILE;
  A  += (long)blockIdx.z * sA;
  Bt += (long)blockIdx.z * sB;
  C  += (long)blockIdx.z * sC;

  f32x4 acc[4][4] = {};

  const int srow = tid >> 2;
  const int scol = (tid & 3) * 8;
  const bf16* Ag0 = A  + (m0 + srow) * (long)lda + scol;
  const bf16* Ag1 = A  + (m0 + 64 + srow) * (long)lda + scol;
  const bf16* Bg0 = Bt + (n0 + srow) * (long)ldb + scol;
  const bf16* Bg1 = Bt + (n0 + 64 + srow) * (long)ldb + scol;
  bf16* Al0 = &As[tid * 8];
  bf16* Al1 = &As[(256 + tid) * 8];
  bf16* Bl0 = &Bs[tid * 8];
  bf16* Bl1 = &Bs[(256 + tid) * 8];

  const int fr = lane & 15, fq = lane >> 4;

  for (int k0 = 0; k0 < K; k0 += BK) {
    __syncthreads();
    gld_lds16(Ag0 + k0, Al0);
    gld_lds16(Ag1 + k0, Al1);
    gld_lds16(Bg0 + k0, Bl0);
    gld_lds16(Bg1 + k0, Bl1);
    __syncthreads();

    bf16x8 af[4], bg[4];
#pragma unroll
    for (int i = 0; i < 4; ++i)
      af[i] = *(const bf16x8*)&As[(wm + i * 16 + fr) * BK + fq * 8];
#pragma unroll
    for (int i = 0; i < 4; ++i)
      bg[i] = *(const bf16x8*)&Bs[(wn + i * 16 + fr) * BK + fq * 8];
#pragma unroll
    for (int mi = 0; mi < 4; ++mi)
#pragma unroll
      for (int ni = 0; ni < 4; ++ni)
        acc[mi][ni] = __builtin_amdgcn_mfma_f32_16x16x32_bf16(
            af[mi], bg[ni], acc[mi][ni], 0, 0, 0);
  }

  const int cc = lane & 15, cq = lane >> 4;
#pragma unroll
  for (int mi = 0; mi < 4; ++mi)
#pragma unroll
    for (int ni = 0; ni < 4; ++ni)
#pragma unroll
      for (int r = 0; r < 4; ++r) {
        int row = wm + mi * 16 + cq * 4 + r;
        int col = wn + ni * 16 + cc;
        C[(m0 + row) * (long)ldc + (n0 + col)] = acc[mi][ni][r] * scale;
      }
}

// ---------------- GEMM: bf16 in, bf16 out packed at f32 row pitch (scores) --
// C is bf16* viewing the f32 attn region: row pitch 4096 bf16 (= 2048 f32),
// batch stride 2048*4096 bf16. Scores land in the low half of each f32 row.
__global__ __launch_bounds__(256, 2)
void gemm_score(const bf16* __restrict__ A, int lda, long sA,
                const bf16* __restrict__ Bt, int ldb, long sB,
                bf16* __restrict__ C, int K, float scale)
{
  __shared__ bf16 As[TILE * BK];
  __shared__ bf16 Bs[TILE * BK];
  const int tid = threadIdx.x;
  const int wave = tid >> 6, lane = tid & 63;
  const int wm = (wave >> 1) * 64, wn = (wave & 1) * 64;
  const long m0 = (long)blockIdx.x * TILE;
  const long n0 = (long)blockIdx.y * TILE;
  A  += (long)blockIdx.z * sA;
  Bt += (long)blockIdx.z * sB;
  C  += (long)blockIdx.z * (2048L * 4096);

  f32x4 acc[4][4] = {};

  const int srow = tid >> 2;
  const int scol = (tid & 3) * 8;
  const bf16* Ag0 = A  + (m0 + srow) * (long)lda + scol;
  const bf16* Ag1 = A  + (m0 + 64 + srow) * (long)lda + scol;
  const bf16* Bg0 = Bt + (n0 + srow) * (long)ldb + scol;
  const bf16* Bg1 = Bt + (n0 + 64 + srow) * (long)ldb + scol;
  bf16* Al0 = &As[tid * 8];
  bf16* Al1 = &As[(256 + tid) * 8];
  bf16* Bl0 = &Bs[tid * 8];
  bf16* Bl1 = &Bs[(256 + tid) * 8];

  const int fr = lane & 15, fq = lane >> 4;

  for (int k0 = 0; k0 < K; k0 += BK) {
    __syncthreads();
    gld_lds16(Ag0 + k0, Al0);
    gld_lds16(Ag1 + k0, Al1);
    gld_lds16(Bg0 + k0, Bl0);
    gld_lds16(Bg1 + k0, Bl1);
    __syncthreads();

    bf16x8 af[4], bg[4];
#pragma unroll
    for (int i = 0; i < 4; ++i)
      af[i] = *(const bf16x8*)&As[(wm + i * 16 + fr) * BK + fq * 8];
#pragma unroll
    for (int i = 0; i < 4; ++i)
      bg[i] = *(const bf16x8*)&Bs[(wn + i * 16 + fr) * BK + fq * 8];
#pragma unroll
    for (int mi = 0; mi < 4; ++mi)
#pragma unroll
      for (int ni = 0; ni < 4; ++ni)
        acc[mi][ni] = __builtin_amdgcn_mfma_f32_16x16x32_bf16(
            af[mi], bg[ni], acc[mi][ni], 0, 0, 0);
  }

  const int cc = lane & 15, cq = lane >> 4;
#pragma unroll
  for (int mi = 0; mi < 4; ++mi)
#pragma unroll
    for (int ni = 0; ni < 4; ++ni)
#pragma unroll
      for (int r = 0; r < 4; ++r) {
        int row = wm + mi * 16 + cq * 4 + r;
        int col = wn + ni * 16 + cc;
        C[(m0 + row) * 4096L + (n0 + col)] = (bf16)(acc[mi][ni][r] * scale);
      }
}

// -------- masked softmax: bf16 packed scores -> f32 in place + bf16 copy ----
// Block = one row. All reads complete before the first barrier; all writes
// happen after the second barrier, so the in-place bf16->f32 overwrite is safe.
__global__ __launch_bounds__(256)
void softmax_mask(const int* __restrict__ mask, float* __restrict__ attn,
                  bf16* __restrict__ attnb)
{
  const int row = blockIdx.x;            // b*2048 + q
  const int b = row >> 11;
  float* arow = attn + (long)row * 2048;
  const bf16* srow_b = (const bf16*)arow;  // packed bf16 scores, cols 0..2047
  bf16* brow = attnb + (long)row * 2048;
  const int* mrow = mask + (b << 11);
  const int tid = threadIdx.x;
  const int lane = tid & 63, wave = tid >> 6;

  bf16x4 sb[2];
  int4 mk[2];
  sb[0] = *(const bf16x4*)&srow_b[tid * 4];
  sb[1] = *(const bf16x4*)&srow_b[1024 + tid * 4];
  mk[0] = *(const int4*)&mrow[tid * 4];
  mk[1] = *(const int4*)&mrow[1024 + tid * 4];
  const int m[8] = {mk[0].x, mk[0].y, mk[0].z, mk[0].w,
                    mk[1].x, mk[1].y, mk[1].z, mk[1].w};
  float s[8];
#pragma unroll
  for (int i = 0; i < 8; ++i) s[i] = (float)sb[i >> 2][i & 3];

  float mx = -3e38f;
#pragma unroll
  for (int i = 0; i < 8; ++i)
    if (m[i]) mx = fmaxf(mx, s[i]);
#pragma unroll
  for (int off = 32; off > 0; off >>= 1) mx = fmaxf(mx, __shfl_xor(mx, off));
  __shared__ float rmax[4], rsum[4];
  if (lane == 0) rmax[wave] = mx;
  __syncthreads();
  mx = fmaxf(fmaxf(rmax[0], rmax[1]), fmaxf(rmax[2], rmax[3]));

  float e[8], sum = 0.f;
#pragma unroll
  for (int i = 0; i < 8; ++i) {
    e[i] = m[i] ? __expf(s[i] - mx) : 0.f;
    sum += e[i];
  }
#pragma unroll
  for (int off = 32; off > 0; off >>= 1) sum += __shfl_xor(sum, off);
  if (lane == 0) rsum[wave] = sum;
  __syncthreads();
  sum = rsum[0] + rsum[1] + rsum[2] + rsum[3];
  float inv = sum > 0.f ? 1.f / sum : 0.f;

  f32x4 o; bf16x4 ob;
#pragma unroll
  for (int h = 0; h < 2; ++h) {
#pragma unroll
    for (int i = 0; i < 4; ++i) {
      float v = e[h * 4 + i] * inv;
      o[i] = v; ob[i] = (bf16)v;
    }
    *(f32x4*)&arow[h * 1024 + tid * 4] = o;
    *(bf16x4*)&brow[h * 1024 + tid * 4] = ob;
  }
}

extern "C" void kernel_launch(void* const* d_in, const int* in_sizes, int n_in,
                              void* d_out, int out_size, void* d_ws, size_t ws_size,
                              hipStream_t stream)
{
  const float* query = (const float*)d_in[0];
  const float* key   = (const float*)d_in[1];
  const float* value = (const float*)d_in[2];
  const int*   mask  = (const int*)d_in[3];
  const float* Wq = (const float*)d_in[4];
  const float* bq = (const float*)d_in[5];
  const float* Wk = (const float*)d_in[6];
  const float* bk = (const float*)d_in[7];
  const float* Wv = (const float*)d_in[8];
  const float* bv = (const float*)d_in[9];

  float* ctx  = (float*)d_out;                       // [8][2048][1024] f32
  float* attn = ctx + (size_t)8 * 2048 * 1024;       // [8][2048][2048] f32

  // ws layout (96 MiB): Pq [0,32M), Pk [32M,64M), PvT [64M,96M) (bf16)
  // attnb (64 MiB bf16) aliases Pq+Pk after they die (post-scores).
  bf16* Pq    = (bf16*)d_ws;
  bf16* Pk    = Pq + (size_t)16384 * 1024;
  bf16* PvT   = Pk + (size_t)16384 * 1024;
  bf16* attnb = (bf16*)d_ws;

  // bf16 scratch for Wq, Wk, value lives in the ctx region of d_out:
  // dead before the final ctx GEMM overwrites it. (37.75 MiB < 64 MiB)
  bf16* Wqb = (bf16*)ctx;
  bf16* Wkb = Wqb + (size_t)1024 * 1024;
  bf16* vb  = Wkb + (size_t)1024 * 1024;

  dim3 blk(256);

  // convert weights + value to bf16 (memory-bound)
  hipLaunchKernelGGL(cvt_f32_bf16, dim3(512), blk, 0, stream, Wq, Wqb, 1024 * 1024);
  hipLaunchKernelGGL(cvt_f32_bf16, dim3(512), blk, 0, stream, Wk, Wkb, 1024 * 1024);
  hipLaunchKernelGGL(cvt_f32_bf16, dim3(8192), blk, 0, stream,
      value, vb, 16384 * 1024);

  // Pq = query·Wqb^T + bq
  hipLaunchKernelGGL(gemm_af32, dim3(128, 8), blk, 0, stream,
      query, 1024, Wqb, 1024, Pq, 1024, bq, 1, 1024);
  // Pk = key·Wkb^T + bk
  hipLaunchKernelGGL(gemm_af32, dim3(128, 8), blk, 0, stream,
      key, 1024, Wkb, 1024, Pk, 1024, bk, 1, 1024);
  // PvT[d][i] = sum_c Wv[d][c]*vb[i][c] + bv[d]
  hipLaunchKernelGGL(gemm_af32, dim3(8, 128), blk, 0, stream,
      Wv, 1024, vb, 1024, PvT, 16384, bv, 2, 1024);
  // raw scores -> bf16 packed in attn region, scale 1/32
  hipLaunchKernelGGL(gemm_score, dim3(16, 16, 8), blk, 0, stream,
      Pq, 1024, (long)2048 * 1024, Pk, 1024, (long)2048 * 1024,
      (bf16*)attn, 1024, 0.03125f);
  // masked softmax: packed bf16 -> f32 in place + bf16 attnb
  hipLaunchKernelGGL(softmax_mask, dim3(16384), blk, 0, stream, mask, attn, attnb);
  // ctx = attnb·Pv
  hipLaunchKernelGGL(gemm_bf16, dim3(16, 8, 8), blk, 0, stream,
      attnb, 2048, (long)2048 * 2048, PvT, 16384, 2048L,
      ctx, 1024, (long)2048 * 1024, 2048, 1.0f);
}

// Round 2
// 681.650 us; speedup vs baseline: 1.1237x; 1.0371x over previous
//
#include <hip/hip_runtime.h>
#include <hip/hip_bf16.h>

// AttentionLayer, B=8, QN=KN=2048, DIN=DPROJ=1024 (all f32 external, bf16 MFMA internal).
// All 5 GEMMs on a 256x256 8-phase double-buffered kernel (m201-style):
//   BK=64, 512 thr (8 waves, 2x4), 128 KiB LDS dbuf, XOR-swizzled LDS
//   (linear gld_lds dest + inverse-swizzled global source + swizzled ds_read),
//   counted vmcnt(4) at tile boundaries (never 0 in steady state),
//   s_setprio(1) around MFMA clusters, raw s_barrier.
// Pipeline: cvt q,k,v,Wq,Wk,Wv -> bf16 (scratch in dead attn region)
//   Pq=qb*Wqb^T+bq, Pk=kb*Wkb^T+bk, PvT=Wvb*vb^T+bv  (bf16 -> ws)
//   S=Pq*Pk^T/32 -> bf16 packed at pitch 4096 into f32 attn rows
//   softmax (packed bf16 -> f32 in place + bf16 attnb -> ws)
//   ctx=attnb*PvT^T -> f32

typedef __bf16 bf16;
typedef __bf16 bf16x4 __attribute__((ext_vector_type(4)));
typedef __bf16 bf16x8 __attribute__((ext_vector_type(8)));
typedef float f32x4 __attribute__((ext_vector_type(4)));

#define BAR() asm volatile("s_barrier" ::: "memory")
#define WAIT_LGKM0() do { asm volatile("s_waitcnt lgkmcnt(0)" ::: "memory"); \
                          __builtin_amdgcn_sched_barrier(0); } while (0)

__device__ __forceinline__ void gld_lds16(const bf16* g, bf16* l) {
  __builtin_amdgcn_global_load_lds(
      (const __attribute__((address_space(1))) void*)g,
      (__attribute__((address_space(3))) void*)l, 16, 0, 0);
}

// ---------------- f32 -> bf16 conversion (memory-bound) ----------------
__global__ __launch_bounds__(256)
void cvt_f32_bf16(const float* __restrict__ src, bf16* __restrict__ dst, int n)
{
  long i = ((long)blockIdx.x * 256 + threadIdx.x) * 8;
  if (i >= n) return;
  f32x4 a = *(const f32x4*)&src[i];
  f32x4 b = *(const f32x4*)&src[i + 4];
  bf16x8 o;
  o[0] = (bf16)a[0]; o[1] = (bf16)a[1]; o[2] = (bf16)a[2]; o[3] = (bf16)a[3];
  o[4] = (bf16)b[0]; o[5] = (bf16)b[1]; o[6] = (bf16)b[2]; o[7] = (bf16)b[3];
  *(bf16x8*)&dst[i] = o;
}

// ---------------- 256x256 8-phase bf16 GEMM ----------------
// C[m][n] = (sum_k A[m][k]*Bt[n][k]) * scale + bias
// LDS per buffer: A 16384 elems (256 rows x 64 cols, 128 B rows) | B 16384.
// Swizzle: physical_byte = row*128 + (col_byte ^ ((row&7)<<4))  (involution).
__global__ __launch_bounds__(512, 2)
void gemm8p(const bf16* __restrict__ A, int lda, long sA,
            const bf16* __restrict__ Bt, int ldb, long sB,
            void* __restrict__ Cout, int ldc, long sC, int c_bf16,
            const float* __restrict__ bias, int bias_mode,
            int K, float scale)
{
  extern __shared__ bf16 lds[];        // 65536 elems = 128 KiB
  const int tid = threadIdx.x;
  const int lane = tid & 63;
  const int wid = tid >> 6;            // 0..7
  const int wr = wid >> 2;             // 0..1 (M)
  const int wc = wid & 3;              // 0..3 (N)
  const long m0 = (long)blockIdx.x * 256;
  const long n0 = (long)blockIdx.y * 256;
  A  += (long)blockIdx.z * sA;
  Bt += (long)blockIdx.z * sB;

  const int fr = lane & 15, fq = lane >> 4;
  // swizzled k-column offsets (elements) for ds_read_b128 of the two 32-wide ksteps
  const int cs0 = (((fq * 16)      ^ ((fr & 7) << 4)) >> 1);
  const int cs1 = (((64 + fq * 16) ^ ((fr & 7) << 4)) >> 1);
  const int rbA = (wr * 128 + fr) * 64;          // + mf*1024 + cs
  const int rbB = 16384 + (wc * 64 + fr) * 64;   // + nf*1024 + cs

  // staging: thread t writes physical LDS bytes t*16 (+i*8192) of a half-tile;
  // inverse swizzle folded into the GLOBAL source column: slot = (t&7)^( (t>>3)&7 )
  const int srow = tid >> 3;                     // 0..63
  const int slot = (tid & 7) ^ (srow & 7);
  const bf16* Ag[4]; const bf16* Bg[4];          // [h*2+i]
#pragma unroll
  for (int h = 0; h < 2; ++h)
#pragma unroll
    for (int i = 0; i < 2; ++i) {
      Ag[h * 2 + i] = A  + (m0 + h * 128 + i * 64 + srow) * (long)lda + slot * 8;
      Bg[h * 2 + i] = Bt + (n0 + h * 128 + i * 64 + srow) * (long)ldb + slot * 8;
    }
  const int ldst = tid * 8;                      // elements

  const int NT = K >> 6;
  f32x4 acc[8][4] = {};

  // ---- prologue: stage t0{A,B} -> buf0, t1{B} -> buf1 (12 loads/thread)
#pragma unroll
  for (int hi = 0; hi < 4; ++hi)
    gld_lds16(Ag[hi], &lds[(hi >> 1) * 8192 + (hi & 1) * 4096 + ldst]);
#pragma unroll
  for (int hi = 0; hi < 4; ++hi)
    gld_lds16(Bg[hi], &lds[16384 + (hi >> 1) * 8192 + (hi & 1) * 4096 + ldst]);
#pragma unroll
  for (int hi = 0; hi < 4; ++hi)
    gld_lds16(Bg[hi] + 64, &lds[49152 + (hi >> 1) * 8192 + (hi & 1) * 4096 + ldst]);
  asm volatile("s_waitcnt vmcnt(4)" ::: "memory");   // t0 landed; t1 B in flight
  BAR();

  for (int t = 0; t < NT; ++t) {
    const int bo  = (t & 1) << 15;     // active buffer (elements)
    const int nbo = bo ^ 32768;
    const int kof  = (t + 1) * 64;
    const int kof2 = (t + 2) * 64;
    const bool st1 = (t + 1 < NT), st2 = (t + 2 < NT);

    bf16x8 a0[4][2], b0[2][2], b1[2][2];

    // ---- phase 0: read A mf0-3 + B nf0-1; stage t+1 A h0 -> nbo
#pragma unroll
    for (int mf = 0; mf < 4; ++mf) {
      a0[mf][0] = *(const bf16x8*)&lds[bo + rbA + mf * 1024 + cs0];
      a0[mf][1] = *(const bf16x8*)&lds[bo + rbA + mf * 1024 + cs1];
    }
#pragma unroll
    for (int nf = 0; nf < 2; ++nf) {
      b0[nf][0] = *(const bf16x8*)&lds[bo + rbB + nf * 1024 + cs0];
      b0[nf][1] = *(const bf16x8*)&lds[bo + rbB + nf * 1024 + cs1];
    }
    if (st1) {
      gld_lds16(Ag[0] + kof, &lds[nbo + ldst]);
      gld_lds16(Ag[1] + kof, &lds[nbo + 4096 + ldst]);
    }
    BAR(); WAIT_LGKM0();
    __builtin_amdgcn_s_setprio(1);
#pragma unroll
    for (int mf = 0; mf < 4; ++mf)
#pragma unroll
      for (int nf = 0; nf < 2; ++nf) {
        acc[mf][nf] = __builtin_amdgcn_mfma_f32_16x16x32_bf16(a0[mf][0], b0[nf][0], acc[mf][nf], 0, 0, 0);
        acc[mf][nf] = __builtin_amdgcn_mfma_f32_16x16x32_bf16(a0[mf][1], b0[nf][1], acc[mf][nf], 0, 0, 0);
      }
    __builtin_amdgcn_s_setprio(0);
    BAR();

    // ---- phase 1: read B nf2-3; stage t+1 A h1 -> nbo
#pragma unroll
    for (int nf = 0; nf < 2; ++nf) {
      b1[nf][0] = *(const bf16x8*)&lds[bo + rbB + (nf + 2) * 1024 + cs0];
      b1[nf][1] = *(const bf16x8*)&lds[bo + rbB + (nf + 2) * 1024 + cs1];
    }
    if (st1) {
      gld_lds16(Ag[2] + kof, &lds[nbo + 8192 + ldst]);
      gld_lds16(Ag[3] + kof, &lds[nbo + 8192 + 4096 + ldst]);
    }
    BAR(); WAIT_LGKM0();
    __builtin_amdgcn_s_setprio(1);
#pragma unroll
    for (int mf = 0; mf < 4; ++mf)
#pragma unroll
      for (int nf = 0; nf < 2; ++nf) {
        acc[mf][nf + 2] = __builtin_amdgcn_mfma_f32_16x16x32_bf16(a0[mf][0], b1[nf][0], acc[mf][nf + 2], 0, 0, 0);
        acc[mf][nf + 2] = __builtin_amdgcn_mfma_f32_16x16x32_bf16(a0[mf][1], b1[nf][1], acc[mf][nf + 2], 0, 0, 0);
      }
    __builtin_amdgcn_s_setprio(0);
    BAR();

    // ---- phase 2: read A mf4-7 (reuse regs); stage t+2 B h0 -> bo
    //      (all B reads of this tile retired at phase-1 lgkmcnt + barrier)
#pragma unroll
    for (int mf = 0; mf < 4; ++mf) {
      a0[mf][0] = *(const bf16x8*)&lds[bo + rbA + (mf + 4) * 1024 + cs0];
      a0[mf][1] = *(const bf16x8*)&lds[bo + rbA + (mf + 4) * 1024 + cs1];
    }
    if (st2) {
      gld_lds16(Bg[0] + kof2, &lds[bo + 16384 + ldst]);
      gld_lds16(Bg[1] + kof2, &lds[bo + 16384 + 4096 + ldst]);
    }
    BAR(); WAIT_LGKM0();
    __builtin_amdgcn_s_setprio(1);
#pragma unroll
    for (int mf = 0; mf < 4; ++mf)
#pragma unroll
      for (int nf = 0; nf < 2; ++nf) {
        acc[mf + 4][nf + 2] = __builtin_amdgcn_mfma_f32_16x16x32_bf16(a0[mf][0], b1[nf][0], acc[mf + 4][nf + 2], 0, 0, 0);
        acc[mf + 4][nf + 2] = __builtin_amdgcn_mfma_f32_16x16x32_bf16(a0[mf][1], b1[nf][1], acc[mf + 4][nf + 2], 0, 0, 0);
      }
    __builtin_amdgcn_s_setprio(0);
    BAR();

    // ---- phase 3: stage t+2 B h1 -> bo; counted vmcnt at tile boundary
    if (st2) {
      gld_lds16(Bg[2] + kof2, &lds[bo + 16384 + 8192 + ldst]);
      gld_lds16(Bg[3] + kof2, &lds[bo + 16384 + 8192 + 4096 + ldst]);
      asm volatile("s_waitcnt vmcnt(4)" ::: "memory");  // t+1 fully landed
    } else {
      asm volatile("s_waitcnt vmcnt(0)" ::: "memory");  // epilogue drain
    }
    BAR(); WAIT_LGKM0();
    __builtin_amdgcn_s_setprio(1);
#pragma unroll
    for (int mf = 0; mf < 4; ++mf)
#pragma unroll
      for (int nf = 0; nf < 2; ++nf) {
        acc[mf + 4][nf] = __builtin_amdgcn_mfma_f32_16x16x32_bf16(a0[mf][0], b0[nf][0], acc[mf + 4][nf], 0, 0, 0);
        acc[mf + 4][nf] = __builtin_amdgcn_mfma_f32_16x16x32_bf16(a0[mf][1], b0[nf][1], acc[mf + 4][nf], 0, 0, 0);
      }
    __builtin_amdgcn_s_setprio(0);
    BAR();
  }

  // ---- epilogue: C/D layout col=lane&15, row=(lane>>4)*4+reg
  const int cc = lane & 15, cq = lane >> 4;
  const long crow0 = m0 + wr * 128;
  const long ccol0 = n0 + wc * 64;
  if (c_bf16) {
    bf16* C = (bf16*)Cout + (long)blockIdx.z * sC;
#pragma unroll
    for (int mf = 0; mf < 8; ++mf)
#pragma unroll
      for (int nf = 0; nf < 4; ++nf)
#pragma unroll
        for (int r = 0; r < 4; ++r) {
          long row = crow0 + mf * 16 + cq * 4 + r;
          long col = ccol0 + nf * 16 + cc;
          float v = acc[mf][nf][r] * scale;
          if (bias_mode == 1) v += bias[col];
          else if (bias_mode == 2) v += bias[row];
          C[row * (long)ldc + col] = (bf16)v;
        }
  } else {
    float* C = (float*)Cout + (long)blockIdx.z * sC;
#pragma unroll
    for (int mf = 0; mf < 8; ++mf)
#pragma unroll
      for (int nf = 0; nf < 4; ++nf)
#pragma unroll
        for (int r = 0; r < 4; ++r) {
          long row = crow0 + mf * 16 + cq * 4 + r;
          long col = ccol0 + nf * 16 + cc;
          float v = acc[mf][nf][r] * scale;
          if (bias_mode == 1) v += bias[col];
          else if (bias_mode == 2) v += bias[row];
          C[row * (long)ldc + col] = v;
        }
  }
}

// -------- masked softmax: bf16 packed scores -> f32 in place + bf16 copy ----
__global__ __launch_bounds__(256)
void softmax_mask(const int* __restrict__ mask, float* __restrict__ attn,
                  bf16* __restrict__ attnb)
{
  const int row = blockIdx.x;            // b*2048 + q
  const int b = row >> 11;
  float* arow = attn + (long)row * 2048;
  const bf16* srow_b = (const bf16*)arow;  // packed bf16 scores, cols 0..2047
  bf16* brow = attnb + (long)row * 2048;
  const int* mrow = mask + (b << 11);
  const int tid = threadIdx.x;
  const int lane = tid & 63, wave = tid >> 6;

  bf16x4 sb[2];
  int4 mk[2];
  sb[0] = *(const bf16x4*)&srow_b[tid * 4];
  sb[1] = *(const bf16x4*)&srow_b[1024 + tid * 4];
  mk[0] = *(const int4*)&mrow[tid * 4];
  mk[1] = *(const int4*)&mrow[1024 + tid * 4];
  const int m[8] = {mk[0].x, mk[0].y, mk[0].z, mk[0].w,
                    mk[1].x, mk[1].y, mk[1].z, mk[1].w};
  float s[8];
#pragma unroll
  for (int i = 0; i < 8; ++i) s[i] = (float)sb[i >> 2][i & 3];

  float mx = -3e38f;
#pragma unroll
  for (int i = 0; i < 8; ++i)
    if (m[i]) mx = fmaxf(mx, s[i]);
#pragma unroll
  for (int off = 32; off > 0; off >>= 1) mx = fmaxf(mx, __shfl_xor(mx, off));
  __shared__ float rmax[4], rsum[4];
  if (lane == 0) rmax[wave] = mx;
  __syncthreads();
  mx = fmaxf(fmaxf(rmax[0], rmax[1]), fmaxf(rmax[2], rmax[3]));

  float e[8], sum = 0.f;
#pragma unroll
  for (int i = 0; i < 8; ++i) {
    e[i] = m[i] ? __expf(s[i] - mx) : 0.f;
    sum += e[i];
  }
#pragma unroll
  for (int off = 32; off > 0; off >>= 1) sum += __shfl_xor(sum, off);
  if (lane == 0) rsum[wave] = sum;
  __syncthreads();
  sum = rsum[0] + rsum[1] + rsum[2] + rsum[3];
  float inv = sum > 0.f ? 1.f / sum : 0.f;

  f32x4 o; bf16x4 ob;
#pragma unroll
  for (int h = 0; h < 2; ++h) {
#pragma unroll
    for (int i = 0; i < 4; ++i) {
      float v = e[h * 4 + i] * inv;
      o[i] = v; ob[i] = (bf16)v;
    }
    *(f32x4*)&arow[h * 1024 + tid * 4] = o;
    *(bf16x4*)&brow[h * 1024 + tid * 4] = ob;
  }
}

extern "C" void kernel_launch(void* const* d_in, const int* in_sizes, int n_in,
                              void* d_out, int out_size, void* d_ws, size_t ws_size,
                              hipStream_t stream)
{
  const float* query = (const float*)d_in[0];
  const float* key   = (const float*)d_in[1];
  const float* value = (const float*)d_in[2];
  const int*   mask  = (const int*)d_in[3];
  const float* Wq = (const float*)d_in[4];
  const float* bq = (const float*)d_in[5];
  const float* Wk = (const float*)d_in[6];
  const float* bk = (const float*)d_in[7];
  const float* Wv = (const float*)d_in[8];
  const float* bv = (const float*)d_in[9];

  float* ctx  = (float*)d_out;                       // [8][2048][1024] f32
  float* attn = ctx + (size_t)8 * 2048 * 1024;       // [8][2048][2048] f32

  // ws (96 MiB): Pq | Pk | PvT (bf16); attnb aliases Pq+Pk after scores.
  bf16* Pq    = (bf16*)d_ws;
  bf16* Pk    = Pq + (size_t)16384 * 1024;
  bf16* PvT   = Pk + (size_t)16384 * 1024;
  bf16* attnb = (bf16*)d_ws;

  // bf16 input copies live in the attn region (dead before scores writes it):
  // qb 32MB | kb 32MB | vb 32MB | Wqb 2MB | Wkb 2MB | Wvb 2MB  (102 MB < 128 MiB)
  bf16* qb  = (bf16*)attn;
  bf16* kb  = qb + (size_t)16384 * 1024;
  bf16* vb  = kb + (size_t)16384 * 1024;
  bf16* Wqb = vb + (size_t)16384 * 1024;
  bf16* Wkb = Wqb + (size_t)1024 * 1024;
  bf16* Wvb = Wkb + (size_t)1024 * 1024;

  static bool attr_set = false;
  if (!attr_set) {
    hipFuncSetAttribute(reinterpret_cast<const void*>(gemm8p),
                        hipFuncAttributeMaxDynamicSharedMemorySize, 131072);
    attr_set = true;
  }

  dim3 blk(256), blk8(512);

  hipLaunchKernelGGL(cvt_f32_bf16, dim3(8192), blk, 0, stream, query, qb, 16384 * 1024);
  hipLaunchKernelGGL(cvt_f32_bf16, dim3(8192), blk, 0, stream, key,   kb, 16384 * 1024);
  hipLaunchKernelGGL(cvt_f32_bf16, dim3(8192), blk, 0, stream, value, vb, 16384 * 1024);
  hipLaunchKernelGGL(cvt_f32_bf16, dim3(512),  blk, 0, stream, Wq, Wqb, 1024 * 1024);
  hipLaunchKernelGGL(cvt_f32_bf16, dim3(512),  blk, 0, stream, Wk, Wkb, 1024 * 1024);
  hipLaunchKernelGGL(cvt_f32_bf16, dim3(512),  blk, 0, stream, Wv, Wvb, 1024 * 1024);

  // Pq = qb·Wqb^T + bq   (M=16384, N=1024, K=1024)
  hipLaunchKernelGGL(gemm8p, dim3(64, 4, 1), blk8, 131072, stream,
      qb, 1024, 0L, Wqb, 1024, 0L, (void*)Pq, 1024, 0L, 1, bq, 1, 1024, 1.0f);
  // Pk = kb·Wkb^T + bk
  hipLaunchKernelGGL(gemm8p, dim3(64, 4, 1), blk8, 131072, stream,
      kb, 1024, 0L, Wkb, 1024, 0L, (void*)Pk, 1024, 0L, 1, bk, 1, 1024, 1.0f);
  // PvT[d][i] = Wvb[d]·vb[i] + bv[d]   (M=1024, N=16384, K=1024)
  hipLaunchKernelGGL(gemm8p, dim3(4, 64, 1), blk8, 131072, stream,
      Wvb, 1024, 0L, vb, 1024, 0L, (void*)PvT, 16384, 0L, 1, bv, 2, 1024, 1.0f);
  // scores: bf16 packed at pitch 4096 into f32 attn rows  (per-batch 2048x2048, K=1024)
  hipLaunchKernelGGL(gemm8p, dim3(8, 8, 8), blk8, 131072, stream,
      Pq, 1024, (long)2048 * 1024, Pk, 1024, (long)2048 * 1024,
      (void*)attn, 4096, (long)2048 * 4096, 1, (const float*)nullptr, 0, 1024, 0.03125f);
  // masked softmax: packed bf16 -> f32 in place + bf16 attnb
  hipLaunchKernelGGL(softmax_mask, dim3(16384), blk, 0, stream, mask, attn, attnb);
  // ctx = attnb·Pv   (per-batch 2048x1024, K=2048)
  hipLaunchKernelGGL(gemm8p, dim3(8, 4, 8), blk8, 131072, stream,
      attnb, 2048, (long)2048 * 2048, PvT, 16384, 2048L,
      (void*)ctx, 1024, (long)2048 * 1024, 0, (const float*)nullptr, 0, 2048, 1.0f);
}

// Round 3
// 672.262 us; speedup vs baseline: 1.1394x; 1.0140x over previous
//
#include <hip/hip_runtime.h>
#include <hip/hip_bf16.h>

// AttentionLayer, B=8, QN=KN=2048, DIN=DPROJ=1024 (f32 external, bf16 MFMA internal).
// 256x256 GEMM, BK=64, 512 thr (8 waves 2x4), 128 KiB LDS double-buffer,
// XOR-swizzled LDS (linear gld_lds dest + inverse-swizzled global source +
// swizzled ds_read), 2 phases per K-tile (4 barriers/tile), counted vmcnt(4),
// s_setprio around 32-MFMA clusters.
// Pipeline (7 launches): cvt_all (q,k,v,Wq,Wk,Wv -> bf16 scratch in dead attn
// region) | Pq | Pk | PvT | scores (bf16 packed at pitch 4096 into f32 attn
// rows) | softmax (in place + bf16 attnb) | ctx.

typedef __bf16 bf16;
typedef __bf16 bf16x4 __attribute__((ext_vector_type(4)));
typedef __bf16 bf16x8 __attribute__((ext_vector_type(8)));
typedef float f32x4 __attribute__((ext_vector_type(4)));

#define BAR() asm volatile("s_barrier" ::: "memory")
#define WAIT_LGKM0() do { asm volatile("s_waitcnt lgkmcnt(0)" ::: "memory"); \
                          __builtin_amdgcn_sched_barrier(0); } while (0)

__device__ __forceinline__ void gld_lds16(const bf16* g, bf16* l) {
  __builtin_amdgcn_global_load_lds(
      (const __attribute__((address_space(1))) void*)g,
      (__attribute__((address_space(3))) void*)l, 16, 0, 0);
}

// ---------------- fused f32 -> bf16 conversion (6 segments, 1 launch) -------
__device__ __forceinline__ void cvt8(const float* s, bf16* d, long i) {
  f32x4 a = *(const f32x4*)&s[i];
  f32x4 b = *(const f32x4*)&s[i + 4];
  bf16x8 o;
  o[0] = (bf16)a[0]; o[1] = (bf16)a[1]; o[2] = (bf16)a[2]; o[3] = (bf16)a[3];
  o[4] = (bf16)b[0]; o[5] = (bf16)b[1]; o[6] = (bf16)b[2]; o[7] = (bf16)b[3];
  *(bf16x8*)&d[i] = o;
}

__global__ __launch_bounds__(256)
void cvt_all(const float* __restrict__ s0, bf16* __restrict__ d0, long n0,
             const float* __restrict__ s1, bf16* __restrict__ d1, long n1,
             const float* __restrict__ s2, bf16* __restrict__ d2, long n2,
             const float* __restrict__ s3, bf16* __restrict__ d3, long n3,
             const float* __restrict__ s4, bf16* __restrict__ d4, long n4,
             const float* __restrict__ s5, bf16* __restrict__ d5, long n5)
{
  long g = ((long)blockIdx.x * 256 + threadIdx.x) * 8;
  if (g < n0) { cvt8(s0, d0, g); return; } g -= n0;
  if (g < n1) { cvt8(s1, d1, g); return; } g -= n1;
  if (g < n2) { cvt8(s2, d2, g); return; } g -= n2;
  if (g < n3) { cvt8(s3, d3, g); return; } g -= n3;
  if (g < n4) { cvt8(s4, d4, g); return; } g -= n4;
  if (g < n5) { cvt8(s5, d5, g); return; }
}

// ---------------- 256x256 2-phase-per-tile bf16 GEMM ----------------
// C[m][n] = (sum_k A[m][k]*Bt[n][k]) * scale + bias
// LDS/buffer: A 16384 elems (256 rows x 64, 128 B rows) | B 16384. Dbuf x2.
// Swizzle: physical_byte = row*128 + (col_byte ^ ((row&7)<<4))  (involution).
__global__ __launch_bounds__(512, 2)
void gemm8p(const bf16* __restrict__ A, int lda, long sA,
            const bf16* __restrict__ Bt, int ldb, long sB,
            void* __restrict__ Cout, int ldc, long sC, int c_bf16,
            const float* __restrict__ bias, int bias_mode,
            int K, float scale)
{
  extern __shared__ bf16 lds[];        // 65536 elems = 128 KiB
  const int tid = threadIdx.x;
  const int lane = tid & 63;
  const int wid = tid >> 6;            // 0..7
  const int wr = wid >> 2;             // 0..1 (M)
  const int wc = wid & 3;              // 0..3 (N)
  const long m0 = (long)blockIdx.x * 256;
  const long n0 = (long)blockIdx.y * 256;
  A  += (long)blockIdx.z * sA;
  Bt += (long)blockIdx.z * sB;

  const int fr = lane & 15, fq = lane >> 4;
  // swizzled k-offsets (elements) for ds_read_b128 of the two 32-wide ksteps
  const int cs0 = (((fq * 16)      ^ ((fr & 7) << 4)) >> 1);
  const int cs1 = (((64 + fq * 16) ^ ((fr & 7) << 4)) >> 1);
  const int rbA = (wr * 128 + fr) * 64;          // + mf*1024 + cs
  const int rbB = 16384 + (wc * 64 + fr) * 64;   // + nf*1024 + cs

  // staging: thread t writes physical LDS bytes t*16 of a 64-row half-tile;
  // inverse swizzle folded into the GLOBAL source column.
  const int srow = tid >> 3;                     // 0..63
  const int slot = (tid & 7) ^ (srow & 7);
  const bf16* Ag[4]; const bf16* Bg[4];          // hi = 64-row slab index
#pragma unroll
  for (int hi = 0; hi < 4; ++hi) {
    Ag[hi] = A  + (m0 + hi * 64 + srow) * (long)lda + slot * 8;
    Bg[hi] = Bt + (n0 + hi * 64 + srow) * (long)ldb + slot * 8;
  }
  const int ldst = tid * 8;                      // elements

  const int NT = K >> 6;
  f32x4 acc[8][4] = {};

  // ---- prologue: stage t0{A,B} -> buf0, t1{B} -> buf1 (12 loads/thread)
#pragma unroll
  for (int hi = 0; hi < 4; ++hi)
    gld_lds16(Ag[hi], &lds[hi * 4096 + ldst]);
#pragma unroll
  for (int hi = 0; hi < 4; ++hi)
    gld_lds16(Bg[hi], &lds[16384 + hi * 4096 + ldst]);
#pragma unroll
  for (int hi = 0; hi < 4; ++hi)
    gld_lds16(Bg[hi] + 64, &lds[49152 + hi * 4096 + ldst]);
  asm volatile("s_waitcnt vmcnt(4)" ::: "memory");   // t0 landed; t1 B in flight
  BAR();

  for (int t = 0; t < NT; ++t) {
    const int bo  = (t & 1) << 15;     // active buffer (elements)
    const int nbo = bo ^ 32768;
    const int kof  = (t + 1) * 64;
    const int kof2 = (t + 2) * 64;
    const bool st1 = (t + 1 < NT), st2 = (t + 2 < NT);

    bf16x8 a[4][2], b[4][2];

    // ======== phase 0: stage A(t+1) -> nbo; read a(mf0-3) + b(nf0-3);
    //                   32 MFMA (mf0-3 x nf0-3)
    if (st1) {
#pragma unroll
      for (int hi = 0; hi < 4; ++hi)
        gld_lds16(Ag[hi] + kof, &lds[nbo + hi * 4096 + ldst]);
    }
#pragma unroll
    for (int mf = 0; mf < 4; ++mf) {
      a[mf][0] = *(const bf16x8*)&lds[bo + rbA + mf * 1024 + cs0];
      a[mf][1] = *(const bf16x8*)&lds[bo + rbA + mf * 1024 + cs1];
    }
#pragma unroll
    for (int nf = 0; nf < 4; ++nf) {
      b[nf][0] = *(const bf16x8*)&lds[bo + rbB + nf * 1024 + cs0];
      b[nf][1] = *(const bf16x8*)&lds[bo + rbB + nf * 1024 + cs1];
    }
    asm volatile("s_waitcnt lgkmcnt(8)" ::: "memory");  // absorb half pre-barrier
    BAR(); WAIT_LGKM0();
    __builtin_amdgcn_s_setprio(1);
#pragma unroll
    for (int mf = 0; mf < 4; ++mf)
#pragma unroll
      for (int nf = 0; nf < 4; ++nf) {
        acc[mf][nf] = __builtin_amdgcn_mfma_f32_16x16x32_bf16(a[mf][0], b[nf][0], acc[mf][nf], 0, 0, 0);
        acc[mf][nf] = __builtin_amdgcn_mfma_f32_16x16x32_bf16(a[mf][1], b[nf][1], acc[mf][nf], 0, 0, 0);
      }
    __builtin_amdgcn_s_setprio(0);
    BAR();

    // ======== phase 1: stage B(t+2) -> bo (B reads of tile t all retired at
    //                   ph0 end-barrier); read a(mf4-7); counted vmcnt;
    //                   32 MFMA (mf4-7 x nf0-3, b held in regs)
    if (st2) {
#pragma unroll
      for (int hi = 0; hi < 4; ++hi)
        gld_lds16(Bg[hi] + kof2, &lds[bo + 16384 + hi * 4096 + ldst]);
    }
#pragma unroll
    for (int mf = 0; mf < 4; ++mf) {
      a[mf][0] = *(const bf16x8*)&lds[bo + rbA + (mf + 4) * 1024 + cs0];
      a[mf][1] = *(const bf16x8*)&lds[bo + rbA + (mf + 4) * 1024 + cs1];
    }
    if (st2) {
      asm volatile("s_waitcnt vmcnt(4)" ::: "memory");  // t+1 fully landed
    } else {
      asm volatile("s_waitcnt vmcnt(0)" ::: "memory");  // tail drain
    }
    BAR(); WAIT_LGKM0();
    __builtin_amdgcn_s_setprio(1);
#pragma unroll
    for (int mf = 0; mf < 4; ++mf)
#pragma unroll
      for (int nf = 0; nf < 4; ++nf) {
        acc[mf + 4][nf] = __builtin_amdgcn_mfma_f32_16x16x32_bf16(a[mf][0], b[nf][0], acc[mf + 4][nf], 0, 0, 0);
        acc[mf + 4][nf] = __builtin_amdgcn_mfma_f32_16x16x32_bf16(a[mf][1], b[nf][1], acc[mf + 4][nf], 0, 0, 0);
      }
    __builtin_amdgcn_s_setprio(0);
    BAR();
  }

  // ---- epilogue: C/D layout col=lane&15, row=(lane>>4)*4+reg
  const int cc = lane & 15, cq = lane >> 4;
  const long crow0 = m0 + wr * 128;
  const long ccol0 = n0 + wc * 64;
  if (c_bf16) {
    bf16* C = (bf16*)Cout + (long)blockIdx.z * sC;
#pragma unroll
    for (int mf = 0; mf < 8; ++mf)
#pragma unroll
      for (int nf = 0; nf < 4; ++nf)
#pragma unroll
        for (int r = 0; r < 4; ++r) {
          long row = crow0 + mf * 16 + cq * 4 + r;
          long col = ccol0 + nf * 16 + cc;
          float v = acc[mf][nf][r] * scale;
          if (bias_mode == 1) v += bias[col];
          else if (bias_mode == 2) v += bias[row];
          C[row * (long)ldc + col] = (bf16)v;
        }
  } else {
    float* C = (float*)Cout + (long)blockIdx.z * sC;
#pragma unroll
    for (int mf = 0; mf < 8; ++mf)
#pragma unroll
      for (int nf = 0; nf < 4; ++nf)
#pragma unroll
        for (int r = 0; r < 4; ++r) {
          long row = crow0 + mf * 16 + cq * 4 + r;
          long col = ccol0 + nf * 16 + cc;
          float v = acc[mf][nf][r] * scale;
          if (bias_mode == 1) v += bias[col];
          else if (bias_mode == 2) v += bias[row];
          C[row * (long)ldc + col] = v;
        }
  }
}

// -------- masked softmax: bf16 packed scores -> f32 in place + bf16 copy ----
__global__ __launch_bounds__(256)
void softmax_mask(const int* __restrict__ mask, float* __restrict__ attn,
                  bf16* __restrict__ attnb)
{
  const int row = blockIdx.x;            // b*2048 + q
  const int b = row >> 11;
  float* arow = attn + (long)row * 2048;
  const bf16* srow_b = (const bf16*)arow;  // packed bf16 scores, cols 0..2047
  bf16* brow = attnb + (long)row * 2048;
  const int* mrow = mask + (b << 11);
  const int tid = threadIdx.x;
  const int lane = tid & 63, wave = tid >> 6;

  bf16x4 sb[2];
  int4 mk[2];
  sb[0] = *(const bf16x4*)&srow_b[tid * 4];
  sb[1] = *(const bf16x4*)&srow_b[1024 + tid * 4];
  mk[0] = *(const int4*)&mrow[tid * 4];
  mk[1] = *(const int4*)&mrow[1024 + tid * 4];
  const int m[8] = {mk[0].x, mk[0].y, mk[0].z, mk[0].w,
                    mk[1].x, mk[1].y, mk[1].z, mk[1].w};
  float s[8];
#pragma unroll
  for (int i = 0; i < 8; ++i) s[i] = (float)sb[i >> 2][i & 3];

  float mx = -3e38f;
#pragma unroll
  for (int i = 0; i < 8; ++i)
    if (m[i]) mx = fmaxf(mx, s[i]);
#pragma unroll
  for (int off = 32; off > 0; off >>= 1) mx = fmaxf(mx, __shfl_xor(mx, off));
  __shared__ float rmax[4], rsum[4];
  if (lane == 0) rmax[wave] = mx;
  __syncthreads();
  mx = fmaxf(fmaxf(rmax[0], rmax[1]), fmaxf(rmax[2], rmax[3]));

  float e[8], sum = 0.f;
#pragma unroll
  for (int i = 0; i < 8; ++i) {
    e[i] = m[i] ? __expf(s[i] - mx) : 0.f;
    sum += e[i];
  }
#pragma unroll
  for (int off = 32; off > 0; off >>= 1) sum += __shfl_xor(sum, off);
  if (lane == 0) rsum[wave] = sum;
  __syncthreads();
  sum = rsum[0] + rsum[1] + rsum[2] + rsum[3];
  float inv = sum > 0.f ? 1.f / sum : 0.f;

  f32x4 o; bf16x4 ob;
#pragma unroll
  for (int h = 0; h < 2; ++h) {
#pragma unroll
    for (int i = 0; i < 4; ++i) {
      float v = e[h * 4 + i] * inv;
      o[i] = v; ob[i] = (bf16)v;
    }
    *(f32x4*)&arow[h * 1024 + tid * 4] = o;
    *(bf16x4*)&brow[h * 1024 + tid * 4] = ob;
  }
}

extern "C" void kernel_launch(void* const* d_in, const int* in_sizes, int n_in,
                              void* d_out, int out_size, void* d_ws, size_t ws_size,
                              hipStream_t stream)
{
  const float* query = (const float*)d_in[0];
  const float* key   = (const float*)d_in[1];
  const float* value = (const float*)d_in[2];
  const int*   mask  = (const int*)d_in[3];
  const float* Wq = (const float*)d_in[4];
  const float* bq = (const float*)d_in[5];
  const float* Wk = (const float*)d_in[6];
  const float* bk = (const float*)d_in[7];
  const float* Wv = (const float*)d_in[8];
  const float* bv = (const float*)d_in[9];

  float* ctx  = (float*)d_out;                       // [8][2048][1024] f32
  float* attn = ctx + (size_t)8 * 2048 * 1024;       // [8][2048][2048] f32

  // ws (96 MiB): Pq | Pk | PvT (bf16); attnb aliases Pq+Pk after scores.
  bf16* Pq    = (bf16*)d_ws;
  bf16* Pk    = Pq + (size_t)16384 * 1024;
  bf16* PvT   = Pk + (size_t)16384 * 1024;
  bf16* attnb = (bf16*)d_ws;

  // bf16 input copies in the attn region (dead before scores writes it):
  // qb 32MB | kb 32MB | vb 32MB | Wqb 2MB | Wkb 2MB | Wvb 2MB  (102 MB < 128 MiB)
  bf16* qb  = (bf16*)attn;
  bf16* kb  = qb + (size_t)16384 * 1024;
  bf16* vb  = kb + (size_t)16384 * 1024;
  bf16* Wqb = vb + (size_t)16384 * 1024;
  bf16* Wkb = Wqb + (size_t)1024 * 1024;
  bf16* Wvb = Wkb + (size_t)1024 * 1024;

  static bool attr_set = false;
  if (!attr_set) {
    hipFuncSetAttribute(reinterpret_cast<const void*>(gemm8p),
                        hipFuncAttributeMaxDynamicSharedMemorySize, 131072);
    attr_set = true;
  }

  dim3 blk(256), blk8(512);
  const long NQ = 16384L * 1024, NW = 1024L * 1024;

  // one fused conversion launch: 53477376 elems / 8 / 256 = 26112 blocks
  hipLaunchKernelGGL(cvt_all, dim3(26112), blk, 0, stream,
      query, qb, NQ, key, kb, NQ, value, vb, NQ,
      Wq, Wqb, NW, Wk, Wkb, NW, Wv, Wvb, NW);

  // Pq = qb·Wqb^T + bq   (M=16384, N=1024, K=1024)
  hipLaunchKernelGGL(gemm8p, dim3(64, 4, 1), blk8, 131072, stream,
      qb, 1024, 0L, Wqb, 1024, 0L, (void*)Pq, 1024, 0L, 1, bq, 1, 1024, 1.0f);
  // Pk = kb·Wkb^T + bk
  hipLaunchKernelGGL(gemm8p, dim3(64, 4, 1), blk8, 131072, stream,
      kb, 1024, 0L, Wkb, 1024, 0L, (void*)Pk, 1024, 0L, 1, bk, 1, 1024, 1.0f);
  // PvT[d][i] = Wvb[d]·vb[i] + bv[d]   (M=1024, N=16384, K=1024)
  hipLaunchKernelGGL(gemm8p, dim3(4, 64, 1), blk8, 131072, stream,
      Wvb, 1024, 0L, vb, 1024, 0L, (void*)PvT, 16384, 0L, 1, bv, 2, 1024, 1.0f);
  // scores: bf16 packed at pitch 4096 into f32 attn rows (per batch 2048x2048)
  hipLaunchKernelGGL(gemm8p, dim3(8, 8, 8), blk8, 131072, stream,
      Pq, 1024, (long)2048 * 1024, Pk, 1024, (long)2048 * 1024,
      (void*)attn, 4096, (long)2048 * 4096, 1, (const float*)nullptr, 0, 1024, 0.03125f);
  // masked softmax: packed bf16 -> f32 in place + bf16 attnb
  hipLaunchKernelGGL(softmax_mask, dim3(16384), blk, 0, stream, mask, attn, attnb);
  // ctx = attnb·Pv   (per batch 2048x1024, K=2048)
  hipLaunchKernelGGL(gemm8p, dim3(8, 4, 8), blk8, 131072, stream,
      attnb, 2048, (long)2048 * 2048, PvT, 16384, 2048L,
      (void*)ctx, 1024, (long)2048 * 1024, 0, (const float*)nullptr, 0, 2048, 1.0f);
}